// Round 1
// baseline (7247.116 us; speedup 1.0000x reference)
//
#include <hip/hip_runtime.h>

#define N_NODES 100000
#define N_EDGES 1600000
#define D 64
#define N_LAYERS 5

// ---------------------------------------------------------------------------
// Scatter phase: agg[dst[e]] += h[src[e]] * w[e]
// 16 threads per edge, each handling 4 consecutive dims via float4.
// Lanes 0-15 of a 16-thread group read one 256B node row contiguously ->
// coalesced 4x256B segments per wave instruction.
// ---------------------------------------------------------------------------
__global__ __launch_bounds__(256) void scatter_kernel(
    const float* __restrict__ h, const int* __restrict__ src,
    const int* __restrict__ dst, const float* __restrict__ ew,
    float* __restrict__ agg)
{
    int t = blockIdx.x * 256 + threadIdx.x;
    int e = t >> 4;
    if (e >= N_EDGES) return;
    int q = t & 15;
    int s = src[e];
    int d = dst[e];
    float w = ew[e];
    float4 v = ((const float4*)(h + (size_t)s * D))[q];
    float* o = agg + (size_t)d * D + q * 4;
    atomicAdd(o + 0, v.x * w);
    atomicAdd(o + 1, v.y * w);
    atomicAdd(o + 2, v.z * w);
    atomicAdd(o + 3, v.w * w);
}

// ---------------------------------------------------------------------------
// Dense phase: out[n] = agg[n] @ W_rel + b + h[n] @ W_root  (+ relu)
// Block = 256 threads handles 16 nodes. Weights (2x 64x64) in LDS; 16 rows of
// agg/h in LDS. Thread (g = wave id, d = lane) computes 4 nodes' dim d,
// amortizing the weight reads 4x. sW[k*64+d] at lane=d -> 2-way bank
// aliasing (free). sA/sX reads are wave-uniform -> LDS broadcast.
// ---------------------------------------------------------------------------
__global__ __launch_bounds__(256) void update_kernel(
    const float* __restrict__ hin, const float* __restrict__ agg,
    const float* __restrict__ Wrel, const float* __restrict__ brel,
    const float* __restrict__ Wroot, float* __restrict__ hout, int relu)
{
    __shared__ float sWrel[64 * 64];
    __shared__ float sWroot[64 * 64];
    __shared__ float sb[64];
    __shared__ float sA[16][64];
    __shared__ float sX[16][64];

    for (int i = threadIdx.x; i < 64 * 64; i += 256) {
        sWrel[i]  = Wrel[i];
        sWroot[i] = Wroot[i];
    }
    if (threadIdx.x < 64) sb[threadIdx.x] = brel[threadIdx.x];

    int nbase = blockIdx.x * 16;
    for (int i = threadIdx.x; i < 16 * 64; i += 256) {
        int ln = i >> 6, dd = i & 63;
        int n = nbase + ln;
        float a = 0.f, xx = 0.f;
        if (n < N_NODES) {
            a  = agg[(size_t)n * D + dd];
            xx = hin[(size_t)n * D + dd];
        }
        sA[ln][dd] = a;
        sX[ln][dd] = xx;
    }
    __syncthreads();

    int d = threadIdx.x & 63;
    int g = threadIdx.x >> 6;  // wave id 0..3 -> nodes g*4 .. g*4+3
    float acc0 = sb[d], acc1 = sb[d], acc2 = sb[d], acc3 = sb[d];
    #pragma unroll
    for (int k = 0; k < 64; ++k) {
        float wr = sWrel[k * 64 + d];
        float wo = sWroot[k * 64 + d];
        acc0 += sA[g * 4 + 0][k] * wr + sX[g * 4 + 0][k] * wo;
        acc1 += sA[g * 4 + 1][k] * wr + sX[g * 4 + 1][k] * wo;
        acc2 += sA[g * 4 + 2][k] * wr + sX[g * 4 + 2][k] * wo;
        acc3 += sA[g * 4 + 3][k] * wr + sX[g * 4 + 3][k] * wo;
    }
    if (relu) {
        acc0 = fmaxf(acc0, 0.f);
        acc1 = fmaxf(acc1, 0.f);
        acc2 = fmaxf(acc2, 0.f);
        acc3 = fmaxf(acc3, 0.f);
    }
    int n0 = nbase + g * 4;
    if (n0 + 0 < N_NODES) hout[(size_t)(n0 + 0) * D + d] = acc0;
    if (n0 + 1 < N_NODES) hout[(size_t)(n0 + 1) * D + d] = acc1;
    if (n0 + 2 < N_NODES) hout[(size_t)(n0 + 2) * D + d] = acc2;
    if (n0 + 3 < N_NODES) hout[(size_t)(n0 + 3) * D + d] = acc3;
}

extern "C" void kernel_launch(void* const* d_in, const int* in_sizes, int n_in,
                              void* d_out, int out_size, void* d_ws, size_t ws_size,
                              hipStream_t stream)
{
    const float* x     = (const float*)d_in[0];
    const int*   ei    = (const int*)d_in[1];   // [2, E] int32 (JAX x64 off)
    const float* ew    = (const float*)d_in[2];
    const float* Wrel  = (const float*)d_in[3]; // [5, 64, 64]
    const float* brel  = (const float*)d_in[4]; // [5, 64]
    const float* Wroot = (const float*)d_in[5]; // [5, 64, 64]
    float* out = (float*)d_out;

    const int* src = ei;
    const int* dst = ei + N_EDGES;

    const size_t feat_bytes = (size_t)N_NODES * D * sizeof(float); // 25.6 MB
    char* ws = (char*)d_ws;
    float* agg  = (float*)(ws);
    float* bufA = (float*)(ws + feat_bytes);
    float* bufB = (float*)(ws + 2 * feat_bytes);

    const int scatter_blocks = (N_EDGES * 16) / 256;      // 100000
    const int update_blocks  = (N_NODES + 15) / 16;       // 6250

    const float* hin = x;
    for (int layer = 0; layer < N_LAYERS; ++layer) {
        hipMemsetAsync(agg, 0, feat_bytes, stream);
        scatter_kernel<<<scatter_blocks, 256, 0, stream>>>(hin, src, dst, ew, agg);
        float* hout = (layer == N_LAYERS - 1) ? out
                      : ((layer & 1) ? bufB : bufA);
        update_kernel<<<update_blocks, 256, 0, stream>>>(
            hin, agg, Wrel + (size_t)layer * D * D, brel + (size_t)layer * D,
            Wroot + (size_t)layer * D * D, hout,
            (layer < N_LAYERS - 1) ? 1 : 0);
        hin = hout;
    }
}

// Round 2
// 1320.496 us; speedup vs baseline: 5.4882x; 5.4882x over previous
//
#include <hip/hip_runtime.h>

#define N_NODES 100000
#define N_EDGES 1600000
#define D 64
#define N_LAYERS 5

// ============================ CSR build (once per launch) ====================

__global__ __launch_bounds__(256) void hist_kernel(
    const int* __restrict__ dst, int* __restrict__ counts)
{
    int e = blockIdx.x * 256 + threadIdx.x;
    if (e < N_EDGES) atomicAdd(&counts[dst[e]], 1);
}

// Single-block exclusive scan of counts[0..N) -> rowptr[0..N]; also rewrites
// counts[] in place into row-start cursors for the placement pass.
__global__ __launch_bounds__(1024) void scan_kernel(
    int* __restrict__ counts, int* __restrict__ rowptr)
{
    __shared__ int s[1024];
    const int t = threadIdx.x;
    const int chunk = (N_NODES + 1023) / 1024;  // 98
    const int begin = t * chunk;
    const int end = min(begin + chunk, N_NODES);

    int sum = 0;
    for (int i = begin; i < end; ++i) sum += counts[i];
    s[t] = sum;
    __syncthreads();
    // Hillis-Steele inclusive scan over the 1024 partial sums
    for (int off = 1; off < 1024; off <<= 1) {
        int v = (t >= off) ? s[t - off] : 0;
        __syncthreads();
        s[t] += v;
        __syncthreads();
    }
    int run = s[t] - sum;  // exclusive prefix for this thread's chunk
    for (int i = begin; i < end; ++i) {
        int c = counts[i];
        rowptr[i] = run;
        counts[i] = run;   // becomes the placement cursor
        run += c;
    }
    if (t == 0) rowptr[N_NODES] = s[1023];
}

__global__ __launch_bounds__(256) void place_kernel(
    const int* __restrict__ src, const int* __restrict__ dst,
    const float* __restrict__ ew, int* __restrict__ cursor,
    int* __restrict__ sorted_src, float* __restrict__ sorted_w)
{
    int e = blockIdx.x * 256 + threadIdx.x;
    if (e >= N_EDGES) return;
    int d = dst[e];
    int p = atomicAdd(&cursor[d], 1);
    sorted_src[p] = src[e];
    sorted_w[p] = ew[e];
}

// ====================== Aggregation: wave per node, no atomics ===============
// lane = feature dim. Each edge: one coalesced 256B row read, FMA into regs.
__global__ __launch_bounds__(256) void agg_kernel(
    const float* __restrict__ h, const int* __restrict__ rowptr,
    const int* __restrict__ ssrc, const float* __restrict__ sw,
    float* __restrict__ agg)
{
    int node = (blockIdx.x * 256 + threadIdx.x) >> 6;
    int lane = threadIdx.x & 63;
    if (node >= N_NODES) return;
    int b = rowptr[node];
    int e = rowptr[node + 1];
    float acc = 0.f;
    int i = b;
    for (; i + 1 < e; i += 2) {  // 2x unroll: two gathers in flight
        int s0 = ssrc[i], s1 = ssrc[i + 1];
        float w0 = sw[i], w1 = sw[i + 1];
        float v0 = h[(size_t)s0 * D + lane];
        float v1 = h[(size_t)s1 * D + lane];
        acc += v0 * w0;
        acc += v1 * w1;
    }
    if (i < e) {
        acc += h[(size_t)ssrc[i] * D + lane] * sw[i];
    }
    agg[(size_t)node * D + lane] = acc;
}

// ====================== Dense phase (unchanged from R1) ======================
// out[n] = agg[n] @ W_rel + b + h[n] @ W_root  (+ relu). In-place safe
// (each block only touches its own 16 rows, staged through LDS first).
__global__ __launch_bounds__(256) void update_kernel(
    const float* __restrict__ hin, const float* __restrict__ agg,
    const float* __restrict__ Wrel, const float* __restrict__ brel,
    const float* __restrict__ Wroot, float* __restrict__ hout, int relu)
{
    __shared__ float sWrel[64 * 64];
    __shared__ float sWroot[64 * 64];
    __shared__ float sb[64];
    __shared__ float sA[16][64];
    __shared__ float sX[16][64];

    for (int i = threadIdx.x; i < 64 * 64; i += 256) {
        sWrel[i]  = Wrel[i];
        sWroot[i] = Wroot[i];
    }
    if (threadIdx.x < 64) sb[threadIdx.x] = brel[threadIdx.x];

    int nbase = blockIdx.x * 16;
    for (int i = threadIdx.x; i < 16 * 64; i += 256) {
        int ln = i >> 6, dd = i & 63;
        int n = nbase + ln;
        float a = 0.f, xx = 0.f;
        if (n < N_NODES) {
            a  = agg[(size_t)n * D + dd];
            xx = hin[(size_t)n * D + dd];
        }
        sA[ln][dd] = a;
        sX[ln][dd] = xx;
    }
    __syncthreads();

    int d = threadIdx.x & 63;
    int g = threadIdx.x >> 6;
    float acc0 = sb[d], acc1 = sb[d], acc2 = sb[d], acc3 = sb[d];
    #pragma unroll
    for (int k = 0; k < 64; ++k) {
        float wr = sWrel[k * 64 + d];
        float wo = sWroot[k * 64 + d];
        acc0 += sA[g * 4 + 0][k] * wr + sX[g * 4 + 0][k] * wo;
        acc1 += sA[g * 4 + 1][k] * wr + sX[g * 4 + 1][k] * wo;
        acc2 += sA[g * 4 + 2][k] * wr + sX[g * 4 + 2][k] * wo;
        acc3 += sA[g * 4 + 3][k] * wr + sX[g * 4 + 3][k] * wo;
    }
    if (relu) {
        acc0 = fmaxf(acc0, 0.f);
        acc1 = fmaxf(acc1, 0.f);
        acc2 = fmaxf(acc2, 0.f);
        acc3 = fmaxf(acc3, 0.f);
    }
    int n0 = nbase + g * 4;
    if (n0 + 0 < N_NODES) hout[(size_t)(n0 + 0) * D + d] = acc0;
    if (n0 + 1 < N_NODES) hout[(size_t)(n0 + 1) * D + d] = acc1;
    if (n0 + 2 < N_NODES) hout[(size_t)(n0 + 2) * D + d] = acc2;
    if (n0 + 3 < N_NODES) hout[(size_t)(n0 + 3) * D + d] = acc3;
}

extern "C" void kernel_launch(void* const* d_in, const int* in_sizes, int n_in,
                              void* d_out, int out_size, void* d_ws, size_t ws_size,
                              hipStream_t stream)
{
    const float* x     = (const float*)d_in[0];
    const int*   ei    = (const int*)d_in[1];   // [2, E] int32 (JAX x64 off)
    const float* ew    = (const float*)d_in[2];
    const float* Wrel  = (const float*)d_in[3]; // [5, 64, 64]
    const float* brel  = (const float*)d_in[4]; // [5, 64]
    const float* Wroot = (const float*)d_in[5]; // [5, 64, 64]
    float* out = (float*)d_out;

    const int* src = ei;
    const int* dst = ei + N_EDGES;

    const size_t feat_bytes = (size_t)N_NODES * D * sizeof(float); // 25.6 MB
    char* ws = (char*)d_ws;
    size_t off = 0;
    float* agg        = (float*)(ws + off); off += feat_bytes;
    float* hbuf       = (float*)(ws + off); off += feat_bytes;
    int*   counts     = (int*)(ws + off);   off += 400000;        // also cursor
    int*   rowptr     = (int*)(ws + off);   off += 400016;        // N+1 ints
    int*   sorted_src = (int*)(ws + off);   off += (size_t)N_EDGES * 4;
    float* sorted_w   = (float*)(ws + off); off += (size_t)N_EDGES * 4;

    const int eblocks = (N_EDGES + 255) / 256;        // 6250
    const int ablocks = (N_NODES * 64 + 255) / 256;   // 25000 (wave per node)
    const int ublocks = (N_NODES + 15) / 16;          // 6250

    // ---- CSR build (amortized over all 5 layers) ----
    hipMemsetAsync(counts, 0, N_NODES * sizeof(int), stream);
    hist_kernel<<<eblocks, 256, 0, stream>>>(dst, counts);
    scan_kernel<<<1, 1024, 0, stream>>>(counts, rowptr);
    place_kernel<<<eblocks, 256, 0, stream>>>(src, dst, ew, counts,
                                              sorted_src, sorted_w);

    // ---- 5 GraphConv layers ----
    const float* hin = x;
    for (int layer = 0; layer < N_LAYERS; ++layer) {
        agg_kernel<<<ablocks, 256, 0, stream>>>(hin, rowptr, sorted_src,
                                                sorted_w, agg);
        float* hout = (layer == N_LAYERS - 1) ? out : hbuf;
        update_kernel<<<ublocks, 256, 0, stream>>>(
            hin, agg, Wrel + (size_t)layer * D * D, brel + (size_t)layer * D,
            Wroot + (size_t)layer * D * D, hout,
            (layer < N_LAYERS - 1) ? 1 : 0);
        hin = hout;  // layers 1..4 run in-place on hbuf (block-local rows)
    }
}